// Round 1
// baseline (220.432 us; speedup 1.0000x reference)
//
#include <hip/hip_runtime.h>

// Head forward: q=x@Wq, k=x@Wk, v=x@Wv; out = softmax(causal(q k^T / 32)) @ v
// B=8 T=2048 C=1024 H=128. Inputs f32, output f32, internal bf16 MFMA.

typedef __attribute__((ext_vector_type(8))) short short8;
typedef __attribute__((ext_vector_type(4))) float f32x4;

#define LDS_PAD 40   // bf16 elems per LDS row (32 + 8) -> keeps ds_read_b128 16B-aligned, spreads banks

static __device__ __forceinline__ unsigned short f2bf(float f) {
  unsigned int u = __float_as_uint(f);
  u += 0x7FFF + ((u >> 16) & 1);      // round-to-nearest-even
  return (unsigned short)(u >> 16);
}

// ---------------- Kernel 0: Wt[w][n][k] = W_w[k][n] as bf16 (w: 0=Wq,1=Wk,2=Wv)
__global__ void wtrans_kernel(const float* __restrict__ Wq,
                              const float* __restrict__ Wk,
                              const float* __restrict__ Wv,
                              unsigned short* __restrict__ Wt) {
  int idx = blockIdx.x * blockDim.x + threadIdx.x;   // 0 .. 3*128*1024-1
  int w   = idx >> 17;
  int rem = idx & 131071;
  int n   = rem >> 10;
  int k   = rem & 1023;
  const float* W = (w == 0) ? Wq : (w == 1) ? Wk : Wv;
  Wt[idx] = f2bf(W[k * 128 + n]);
}

// ---------------- Kernel 1: fused QKV GEMM.  M=16384, K=1024, 3 x N=128.
// 256 blocks x 512 thr (8 waves). BM=64, BK=32. Wave w owns cols [16w,16w+16) of each weight.
// x staged f32->bf16 into LDS once, shared across the 3 weights (x read 1x from HBM).
__global__ __launch_bounds__(512) void qkv_kernel(
    const float* __restrict__ x,            // [16384][1024] f32
    const unsigned short* __restrict__ Wt,  // [3][128][1024] bf16
    unsigned short* __restrict__ q,         // [16384][128] bf16
    unsigned short* __restrict__ kb,        // [16384][128] bf16
    unsigned short* __restrict__ vt)        // [8][128][2048] bf16 (v transposed)
{
  __shared__ unsigned short xl[64 * LDS_PAD];
  const int tid  = threadIdx.x;
  const int lane = tid & 63;
  const int wave = tid >> 6;            // 0..7
  const int m0   = blockIdx.x * 64;
  const int lr   = lane & 15;           // A row-in-16 / B col-in-16
  const int lk   = (lane >> 4) * 8;     // k offset within 32

  f32x4 acc[4][3];
  for (int i = 0; i < 4; ++i)
    for (int w = 0; w < 3; ++w) acc[i][w] = (f32x4){0.f, 0.f, 0.f, 0.f};

  const int srow = tid >> 3;            // 0..63
  const int skc  = (tid & 7) * 4;       // 0..28
  const float* xsrc = x + (size_t)(m0 + srow) * 1024 + skc;

  for (int kt = 0; kt < 32; ++kt) {
    float4 v = *reinterpret_cast<const float4*>(xsrc + kt * 32);
    ushort4 u;
    u.x = f2bf(v.x); u.y = f2bf(v.y); u.z = f2bf(v.z); u.w = f2bf(v.w);
    *reinterpret_cast<ushort4*>(&xl[srow * LDS_PAD + skc]) = u;
    __syncthreads();

    short8 af[4];
    #pragma unroll
    for (int mf = 0; mf < 4; ++mf)
      af[mf] = *reinterpret_cast<const short8*>(&xl[(mf * 16 + lr) * LDS_PAD + lk]);

    #pragma unroll
    for (int w = 0; w < 3; ++w) {
      const unsigned short* bp =
          Wt + ((size_t)(w * 128 + wave * 16 + lr)) * 1024 + kt * 32 + lk;
      short8 bfr = *reinterpret_cast<const short8*>(bp);
      #pragma unroll
      for (int mf = 0; mf < 4; ++mf)
        acc[mf][w] = __builtin_amdgcn_mfma_f32_16x16x32_bf16(af[mf], bfr, acc[mf][w], 0, 0, 0);
    }
    __syncthreads();
  }

  // epilogue: C/D layout col=lane&15, row=(lane>>4)*4+reg
  const int h = wave * 16 + lr;
  const int b = m0 >> 11;
  #pragma unroll
  for (int mf = 0; mf < 4; ++mf) {
    int r0 = m0 + mf * 16 + (lane >> 4) * 4;
    #pragma unroll
    for (int j = 0; j < 4; ++j) {
      q [(size_t)(r0 + j) * 128 + h] = f2bf(acc[mf][0][j]);
      kb[(size_t)(r0 + j) * 128 + h] = f2bf(acc[mf][1][j]);
    }
    int t = r0 & 2047;
    ushort4 u;
    u.x = f2bf(acc[mf][2][0]); u.y = f2bf(acc[mf][2][1]);
    u.z = f2bf(acc[mf][2][2]); u.w = f2bf(acc[mf][2][3]);
    *reinterpret_cast<ushort4*>(vt + ((size_t)(b * 128 + h)) * 2048 + t) = u;
  }
}

// ---------------- Kernel 2: causal flash attention. 1 wave per 16 q rows.
// grid (128 qtiles, 8 batches) x 64 thr. KVBLK=32. K/V straight from global (L2-resident).
__global__ __launch_bounds__(64) void attn_kernel(
    const unsigned short* __restrict__ q,   // [8][2048][128]
    const unsigned short* __restrict__ kb,  // [8][2048][128]
    const unsigned short* __restrict__ vt,  // [8][128][2048]
    float* __restrict__ out)                // [8][2048][128] f32
{
  __shared__ unsigned short pl[16 * LDS_PAD];
  const int lane = threadIdx.x;
  const int lr = lane & 15;
  const int lg = lane >> 4;        // 0..3
  const int lk = lg * 8;
  const int b  = blockIdx.y;
  const int t0 = blockIdx.x * 16;

  short8 qf[4];
  const unsigned short* qp = q + ((size_t)(b * 2048 + t0 + lr)) * 128 + lk;
  #pragma unroll
  for (int ks = 0; ks < 4; ++ks)
    qf[ks] = *reinterpret_cast<const short8*>(qp + ks * 32);

  f32x4 o[8];
  #pragma unroll
  for (int n = 0; n < 8; ++n) o[n] = (f32x4){0.f, 0.f, 0.f, 0.f};
  float m[4]    = {-1e30f, -1e30f, -1e30f, -1e30f};
  float lsum[4] = {0.f, 0.f, 0.f, 0.f};

  const unsigned short* kbase = kb + (size_t)b * 2048 * 128;
  const unsigned short* vbase = vt + (size_t)b * 128 * 2048;

  for (int kvb = 0; kvb < t0 + 16; kvb += 32) {
    f32x4 s[2] = {(f32x4){0.f,0.f,0.f,0.f}, (f32x4){0.f,0.f,0.f,0.f}};
    #pragma unroll
    for (int nf = 0; nf < 2; ++nf) {
      const unsigned short* kp = kbase + (size_t)(kvb + nf * 16 + lr) * 128 + lk;
      #pragma unroll
      for (int ks = 0; ks < 4; ++ks) {
        short8 kf = *reinterpret_cast<const short8*>(kp + ks * 32);
        s[nf] = __builtin_amdgcn_mfma_f32_16x16x32_bf16(qf[ks], kf, s[nf], 0, 0, 0);
      }
    }
    const bool maskblk = (kvb + 31 > t0);   // only the diagonal block needs masking
    #pragma unroll
    for (int nf = 0; nf < 2; ++nf)
      #pragma unroll
      for (int j = 0; j < 4; ++j) {
        float sv = s[nf][j] * 0.03125f;     // C^-0.5 = 1/32
        if (maskblk) {
          int c = kvb + nf * 16 + lr;
          int r = t0 + lg * 4 + j;
          if (c > r) sv = -1e30f;
        }
        s[nf][j] = sv;
      }
    // online softmax (rows live in 16-lane groups)
    float p0[4], p1[4], fac[4];
    #pragma unroll
    for (int j = 0; j < 4; ++j) {
      float mx = fmaxf(s[0][j], s[1][j]);
      #pragma unroll
      for (int off = 1; off < 16; off <<= 1) mx = fmaxf(mx, __shfl_xor(mx, off));
      float mn = fmaxf(m[j], mx);
      fac[j] = __expf(m[j] - mn);
      m[j] = mn;
      p0[j] = __expf(s[0][j] - mn);
      p1[j] = __expf(s[1][j] - mn);
      float sm = p0[j] + p1[j];
      #pragma unroll
      for (int off = 1; off < 16; off <<= 1) sm += __shfl_xor(sm, off);
      lsum[j] = lsum[j] * fac[j] + sm;
    }
    #pragma unroll
    for (int n = 0; n < 8; ++n)
      #pragma unroll
      for (int j = 0; j < 4; ++j) o[n][j] *= fac[j];

    // P -> LDS (bf16) to reshape into MFMA A-fragment layout
    #pragma unroll
    for (int j = 0; j < 4; ++j) {
      pl[(lg * 4 + j) * LDS_PAD + lr]      = f2bf(p0[j]);
      pl[(lg * 4 + j) * LDS_PAD + 16 + lr] = f2bf(p1[j]);
    }
    __syncthreads();
    short8 pf = *reinterpret_cast<const short8*>(&pl[lr * LDS_PAD + lk]);
    #pragma unroll
    for (int n = 0; n < 8; ++n) {
      const unsigned short* vp = vbase + (size_t)(n * 16 + lr) * 2048 + kvb + lk;
      short8 vf = *reinterpret_cast<const short8*>(vp);
      o[n] = __builtin_amdgcn_mfma_f32_16x16x32_bf16(pf, vf, o[n], 0, 0, 0);
    }
    __syncthreads();
  }

  float* op = out + ((size_t)(b * 2048 + t0 + lg * 4)) * 128;
  #pragma unroll
  for (int j = 0; j < 4; ++j) {
    float rcp = 1.0f / lsum[j];
    #pragma unroll
    for (int n = 0; n < 8; ++n)
      op[(size_t)j * 128 + n * 16 + lr] = o[n][j] * rcp;
  }
}

extern "C" void kernel_launch(void* const* d_in, const int* in_sizes, int n_in,
                              void* d_out, int out_size, void* d_ws, size_t ws_size,
                              hipStream_t stream) {
  const float* x  = (const float*)d_in[0];
  const float* Wk = (const float*)d_in[1];
  const float* Wq = (const float*)d_in[2];
  const float* Wv = (const float*)d_in[3];
  float* out = (float*)d_out;

  char* ws = (char*)d_ws;
  unsigned short* q  = (unsigned short*)(ws);                  // 4 MB
  unsigned short* kb = (unsigned short*)(ws + (4u  << 20));    // 4 MB
  unsigned short* vt = (unsigned short*)(ws + (8u  << 20));    // 4 MB
  unsigned short* Wt = (unsigned short*)(ws + (12u << 20));    // 768 KB

  wtrans_kernel<<<dim3(1536), dim3(256), 0, stream>>>(Wq, Wk, Wv, Wt);
  qkv_kernel<<<dim3(256), dim3(512), 0, stream>>>(x, Wt, q, kb, vt);
  attn_kernel<<<dim3(128, 8), dim3(64), 0, stream>>>(q, kb, vt, out);
}

// Round 2
// 209.142 us; speedup vs baseline: 1.0540x; 1.0540x over previous
//
#include <hip/hip_runtime.h>

// Head forward: q=x@Wq, k=x@Wk, v=x@Wv; out = softmax(causal(q k^T / 32)) @ v
// B=8 T=2048 C=1024 H=128. Inputs f32, output f32, internal bf16 MFMA.

typedef __attribute__((ext_vector_type(8))) short short8;
typedef __attribute__((ext_vector_type(4))) float f32x4;

#define LDS_PAD 40   // bf16 elems per LDS row for qkv staging

static __device__ __forceinline__ unsigned short f2bf(float f) {
  unsigned int u = __float_as_uint(f);
  u += 0x7FFF + ((u >> 16) & 1);      // round-to-nearest-even
  return (unsigned short)(u >> 16);
}

// ---------------- Kernel 0: Wt[w][n][k] = W_w[k][n] as bf16 (w: 0=Wq,1=Wk,2=Wv)
__global__ void wtrans_kernel(const float* __restrict__ Wq,
                              const float* __restrict__ Wk,
                              const float* __restrict__ Wv,
                              unsigned short* __restrict__ Wt) {
  int idx = blockIdx.x * blockDim.x + threadIdx.x;   // 0 .. 3*128*1024-1
  int w   = idx >> 17;
  int rem = idx & 131071;
  int n   = rem >> 10;
  int k   = rem & 1023;
  const float* W = (w == 0) ? Wq : (w == 1) ? Wk : Wv;
  Wt[idx] = f2bf(W[k * 128 + n]);
}

// ---------------- Kernel 1: fused QKV GEMM.  M=16384, K=1024, 3 x N=128.
__global__ __launch_bounds__(512) void qkv_kernel(
    const float* __restrict__ x,            // [16384][1024] f32
    const unsigned short* __restrict__ Wt,  // [3][128][1024] bf16
    unsigned short* __restrict__ q,         // [16384][128] bf16
    unsigned short* __restrict__ kb,        // [16384][128] bf16
    unsigned short* __restrict__ vt)        // [8][128][2048] bf16 (v transposed)
{
  __shared__ unsigned short xl[64 * LDS_PAD];
  const int tid  = threadIdx.x;
  const int lane = tid & 63;
  const int wave = tid >> 6;            // 0..7
  const int m0   = blockIdx.x * 64;
  const int lr   = lane & 15;           // A row-in-16 / B col-in-16
  const int lk   = (lane >> 4) * 8;     // k offset within 32

  f32x4 acc[4][3];
  for (int i = 0; i < 4; ++i)
    for (int w = 0; w < 3; ++w) acc[i][w] = (f32x4){0.f, 0.f, 0.f, 0.f};

  const int srow = tid >> 3;            // 0..63
  const int skc  = (tid & 7) * 4;       // 0..28
  const float* xsrc = x + (size_t)(m0 + srow) * 1024 + skc;

  for (int kt = 0; kt < 32; ++kt) {
    float4 v = *reinterpret_cast<const float4*>(xsrc + kt * 32);
    ushort4 u;
    u.x = f2bf(v.x); u.y = f2bf(v.y); u.z = f2bf(v.z); u.w = f2bf(v.w);
    *reinterpret_cast<ushort4*>(&xl[srow * LDS_PAD + skc]) = u;
    __syncthreads();

    short8 af[4];
    #pragma unroll
    for (int mf = 0; mf < 4; ++mf)
      af[mf] = *reinterpret_cast<const short8*>(&xl[(mf * 16 + lr) * LDS_PAD + lk]);

    #pragma unroll
    for (int w = 0; w < 3; ++w) {
      const unsigned short* bp =
          Wt + ((size_t)(w * 128 + wave * 16 + lr)) * 1024 + kt * 32 + lk;
      short8 bfr = *reinterpret_cast<const short8*>(bp);
      #pragma unroll
      for (int mf = 0; mf < 4; ++mf)
        acc[mf][w] = __builtin_amdgcn_mfma_f32_16x16x32_bf16(af[mf], bfr, acc[mf][w], 0, 0, 0);
    }
    __syncthreads();
  }

  const int h = wave * 16 + lr;
  const int b = m0 >> 11;
  #pragma unroll
  for (int mf = 0; mf < 4; ++mf) {
    int r0 = m0 + mf * 16 + (lane >> 4) * 4;
    #pragma unroll
    for (int j = 0; j < 4; ++j) {
      q [(size_t)(r0 + j) * 128 + h] = f2bf(acc[mf][0][j]);
      kb[(size_t)(r0 + j) * 128 + h] = f2bf(acc[mf][1][j]);
    }
    int t = r0 & 2047;
    ushort4 u;
    u.x = f2bf(acc[mf][2][0]); u.y = f2bf(acc[mf][2][1]);
    u.z = f2bf(acc[mf][2][2]); u.w = f2bf(acc[mf][2][3]);
    *reinterpret_cast<ushort4*>(vt + ((size_t)(b * 128 + h)) * 2048 + t) = u;
  }
}

// ---------------- Kernel 2: causal flash attention, swapped-QK^T layout.
// 1 wave per 16 q rows, KVBLK=64. Lane owns q-row (lane&15): softmax is
// in-register + 2 shfl_xor. Largest qtiles launched first (LPT balance).
__global__ __launch_bounds__(64) void attn_kernel(
    const unsigned short* __restrict__ q,   // [8][2048][128]
    const unsigned short* __restrict__ kb,  // [8][2048][128]
    const unsigned short* __restrict__ vt,  // [8][128][2048]
    float* __restrict__ out)                // [8][2048][128] f32
{
  __shared__ unsigned short pl[16 * 72];    // P tile [16 q][64 kv], pad to 72
  const int lane = threadIdx.x;
  const int lr = lane & 15;                 // q-row owned by this lane
  const int lg = lane >> 4;                 // 0..3
  const int b  = blockIdx.y;
  const int qt = (int)gridDim.x - 1 - (int)blockIdx.x;   // largest-first
  const int t0 = qt * 16;

  // Q fragment (used as MFMA *B* operand): lane holds q-row lr, h=ks*32+lg*8..
  short8 qf[4];
  const unsigned short* qp = q + ((size_t)(b * 2048 + t0 + lr)) * 128 + lg * 8;
  #pragma unroll
  for (int ks = 0; ks < 4; ++ks)
    qf[ks] = *reinterpret_cast<const short8*>(qp + ks * 32);

  f32x4 o[8];
  #pragma unroll
  for (int n = 0; n < 8; ++n) o[n] = (f32x4){0.f, 0.f, 0.f, 0.f};
  float mrow = -1e30f;   // running max (log2 domain), for q-row lr
  float lrow = 0.f;      // running denom, for q-row lr

  const unsigned short* kbase = kb + (size_t)b * 2048 * 128;
  const unsigned short* vbase = vt + (size_t)b * 128 * 2048;
  const float SC = 0.03125f * 1.44269504f;  // C^-0.5 * log2(e)

  for (int kvb = 0; kvb < t0 + 16; kvb += 64) {
    const int nvis = min(4, (t0 + 15 - kvb) / 16 + 1);  // visible 16-wide kv tiles

    // S^T = K_tile * Q^T : C col = q (lane&15), C row = kv-in-tile
    f32x4 sT[4];
    #pragma unroll
    for (int nf = 0; nf < 4; ++nf) {
      if (nf >= nvis) break;
      sT[nf] = (f32x4){0.f, 0.f, 0.f, 0.f};
      const unsigned short* kp = kbase + (size_t)(kvb + nf * 16 + lr) * 128 + lg * 8;
      #pragma unroll
      for (int ks = 0; ks < 4; ++ks) {
        short8 kf = *reinterpret_cast<const short8*>(kp + ks * 32);
        sT[nf] = __builtin_amdgcn_mfma_f32_16x16x32_bf16(kf, qf[ks], sT[nf], 0, 0, 0);
      }
    }

    // scale+mask; per-lane row max over this block's kv
    float sc[4][4];
    float pm = -1e30f;
    const int myrow = t0 + lr;
    #pragma unroll
    for (int nf = 0; nf < 4; ++nf) {
      if (nf >= nvis) break;
      #pragma unroll
      for (int j = 0; j < 4; ++j) {
        int kv = kvb + nf * 16 + lg * 4 + j;
        float v = (kv <= myrow) ? sT[nf][j] * SC : -1e30f;
        sc[nf][j] = v;
        pm = fmaxf(pm, v);
      }
    }
    pm = fmaxf(pm, __shfl_xor(pm, 16));
    pm = fmaxf(pm, __shfl_xor(pm, 32));
    float mnew = fmaxf(mrow, pm);
    float fac = exp2f(mrow - mnew);
    mrow = mnew;

    float p[4][4];
    float ps = 0.f;
    #pragma unroll
    for (int nf = 0; nf < 4; ++nf) {
      if (nf >= nvis) break;
      #pragma unroll
      for (int j = 0; j < 4; ++j) {
        p[nf][j] = exp2f(sc[nf][j] - mnew);
        ps += p[nf][j];
      }
    }
    ps += __shfl_xor(ps, 16);
    ps += __shfl_xor(ps, 32);
    lrow = lrow * fac + ps;

    // rescale o: o-row r=(lg*4+j) needs fac from a lane with lane&15 == r
    float facr[4];
    #pragma unroll
    for (int j = 0; j < 4; ++j)
      facr[j] = __shfl(fac, (lane & 48) | (lg * 4 + j));
    #pragma unroll
    for (int n = 0; n < 8; ++n)
      #pragma unroll
      for (int j = 0; j < 4; ++j) o[n][j] *= facr[j];

    // P -> LDS: lane owns q-row lr, kv = nf*16 + lg*4 + j (4 contiguous per nf)
    #pragma unroll
    for (int nf = 0; nf < 4; ++nf) {
      ushort4 u;
      if (nf < nvis) {
        u.x = f2bf(p[nf][0]); u.y = f2bf(p[nf][1]);
        u.z = f2bf(p[nf][2]); u.w = f2bf(p[nf][3]);
      } else {
        u.x = u.y = u.z = u.w = 0;
      }
      *reinterpret_cast<ushort4*>(&pl[lr * 72 + nf * 16 + lg * 4]) = u;
    }
    __syncthreads();

    // PV: A-frag = P (lane: row lr, k=ks*32+lg*8..), B-frag = V^T slice
    short8 pf0 = *reinterpret_cast<const short8*>(&pl[lr * 72 + lg * 8]);
    short8 pf1 = *reinterpret_cast<const short8*>(&pl[lr * 72 + 32 + lg * 8]);
    const int ksmax = (nvis + 1) >> 1;
    #pragma unroll
    for (int ks = 0; ks < 2; ++ks) {
      if (ks >= ksmax) break;
      short8 pf = ks ? pf1 : pf0;
      #pragma unroll
      for (int n = 0; n < 8; ++n) {
        const unsigned short* vp = vbase + (size_t)(n * 16 + lr) * 2048 + kvb + ks * 32 + lg * 8;
        short8 vf = *reinterpret_cast<const short8*>(vp);
        o[n] = __builtin_amdgcn_mfma_f32_16x16x32_bf16(pf, vf, o[n], 0, 0, 0);
      }
    }
    __syncthreads();
  }

  // epilogue: o-row r=(lg*4+j) needs 1/lrow from lane with lane&15 == r
  float rr = 1.0f / lrow;
  float rcp[4];
  #pragma unroll
  for (int j = 0; j < 4; ++j)
    rcp[j] = __shfl(rr, (lane & 48) | (lg * 4 + j));

  float* op = out + ((size_t)(b * 2048 + t0 + lg * 4)) * 128;
  #pragma unroll
  for (int j = 0; j < 4; ++j)
    #pragma unroll
    for (int n = 0; n < 8; ++n)
      op[(size_t)j * 128 + n * 16 + lr] = o[n][j] * rcp[j];
}

extern "C" void kernel_launch(void* const* d_in, const int* in_sizes, int n_in,
                              void* d_out, int out_size, void* d_ws, size_t ws_size,
                              hipStream_t stream) {
  const float* x  = (const float*)d_in[0];
  const float* Wk = (const float*)d_in[1];
  const float* Wq = (const float*)d_in[2];
  const float* Wv = (const float*)d_in[3];
  float* out = (float*)d_out;

  char* ws = (char*)d_ws;
  unsigned short* q  = (unsigned short*)(ws);                  // 4 MB
  unsigned short* kb = (unsigned short*)(ws + (4u  << 20));    // 4 MB
  unsigned short* vt = (unsigned short*)(ws + (8u  << 20));    // 4 MB
  unsigned short* Wt = (unsigned short*)(ws + (12u << 20));    // 768 KB

  wtrans_kernel<<<dim3(1536), dim3(256), 0, stream>>>(Wq, Wk, Wv, Wt);
  qkv_kernel<<<dim3(256), dim3(512), 0, stream>>>(x, Wt, q, kb, vt);
  attn_kernel<<<dim3(128, 8), dim3(64), 0, stream>>>(q, kb, vt, out);
}

// Round 4
// 126.952 us; speedup vs baseline: 1.7363x; 1.6474x over previous
//
#include <hip/hip_runtime.h>

// Head forward: q=x@Wq, k=x@Wk, v=x@Wv; out = softmax(causal(q k^T / 32)) @ v
// B=8 T=2048 C=1024 H=128. Inputs f32, output f32, internal bf16 MFMA.

typedef __attribute__((ext_vector_type(8))) short short8;
typedef __attribute__((ext_vector_type(4))) float f32x4;

#define LDS_PAD 40   // bf16 elems per LDS row for qkv staging

static __device__ __forceinline__ unsigned short f2bf(float f) {
  unsigned int u = __float_as_uint(f);
  u += 0x7FFF + ((u >> 16) & 1);      // round-to-nearest-even
  return (unsigned short)(u >> 16);
}

// ---------------- Kernel 0: Wt[w][n][k] = W_w[k][n] as bf16 (w: 0=Wq,1=Wk,2=Wv)
__global__ void wtrans_kernel(const float* __restrict__ Wq,
                              const float* __restrict__ Wk,
                              const float* __restrict__ Wv,
                              unsigned short* __restrict__ Wt) {
  int idx = blockIdx.x * blockDim.x + threadIdx.x;   // 0 .. 3*128*1024-1
  int w   = idx >> 17;
  int rem = idx & 131071;
  int n   = rem >> 10;
  int k   = rem & 1023;
  const float* W = (w == 0) ? Wq : (w == 1) ? Wk : Wv;
  Wt[idx] = f2bf(W[k * 128 + n]);
}

// ---------------- Kernel 1: fused QKV GEMM.  M=16384, K=1024, 3 x N=128.
__global__ __launch_bounds__(512) void qkv_kernel(
    const float* __restrict__ x,            // [16384][1024] f32
    const unsigned short* __restrict__ Wt,  // [3][128][1024] bf16
    unsigned short* __restrict__ q,         // [16384][128] bf16
    unsigned short* __restrict__ kb,        // [16384][128] bf16
    unsigned short* __restrict__ vt)        // [8][128][2048] bf16 (v transposed)
{
  __shared__ unsigned short xl[64 * LDS_PAD];
  const int tid  = threadIdx.x;
  const int lane = tid & 63;
  const int wave = tid >> 6;            // 0..7
  const int m0   = blockIdx.x * 64;
  const int lr   = lane & 15;           // A row-in-16 / B col-in-16
  const int lk   = (lane >> 4) * 8;     // k offset within 32

  f32x4 acc[4][3];
  for (int i = 0; i < 4; ++i)
    for (int w = 0; w < 3; ++w) acc[i][w] = (f32x4){0.f, 0.f, 0.f, 0.f};

  const int srow = tid >> 3;            // 0..63
  const int skc  = (tid & 7) * 4;       // 0..28
  const float* xsrc = x + (size_t)(m0 + srow) * 1024 + skc;

  for (int kt = 0; kt < 32; ++kt) {
    float4 v = *reinterpret_cast<const float4*>(xsrc + kt * 32);
    ushort4 u;
    u.x = f2bf(v.x); u.y = f2bf(v.y); u.z = f2bf(v.z); u.w = f2bf(v.w);
    *reinterpret_cast<ushort4*>(&xl[srow * LDS_PAD + skc]) = u;
    __syncthreads();

    short8 af[4];
    #pragma unroll
    for (int mf = 0; mf < 4; ++mf)
      af[mf] = *reinterpret_cast<const short8*>(&xl[(mf * 16 + lr) * LDS_PAD + lk]);

    #pragma unroll
    for (int w = 0; w < 3; ++w) {
      const unsigned short* bp =
          Wt + ((size_t)(w * 128 + wave * 16 + lr)) * 1024 + kt * 32 + lk;
      short8 bfr = *reinterpret_cast<const short8*>(bp);
      #pragma unroll
      for (int mf = 0; mf < 4; ++mf)
        acc[mf][w] = __builtin_amdgcn_mfma_f32_16x16x32_bf16(af[mf], bfr, acc[mf][w], 0, 0, 0);
    }
    __syncthreads();
  }

  const int h = wave * 16 + lr;
  const int b = m0 >> 11;
  #pragma unroll
  for (int mf = 0; mf < 4; ++mf) {
    int r0 = m0 + mf * 16 + (lane >> 4) * 4;
    #pragma unroll
    for (int j = 0; j < 4; ++j) {
      q [(size_t)(r0 + j) * 128 + h] = f2bf(acc[mf][0][j]);
      kb[(size_t)(r0 + j) * 128 + h] = f2bf(acc[mf][1][j]);
    }
    int t = r0 & 2047;
    ushort4 u;
    u.x = f2bf(acc[mf][2][0]); u.y = f2bf(acc[mf][2][1]);
    u.z = f2bf(acc[mf][2][2]); u.w = f2bf(acc[mf][2][3]);
    *reinterpret_cast<ushort4*>(vt + ((size_t)(b * 128 + h)) * 2048 + t) = u;
  }
}

// ---------------- Kernel 2: causal flash attention v4.
// 1 wave / 16 q-rows, KVBLK=64, no LDS/barriers/shuffle-redistribution.
// Swapped QK^T with PERMUTED K-row order: tile nf loads K row
//   kv = (nf>>1)*32 + (r>>2)*8 + (nf&1)*4 + (r&3)   (r = A-frag row = lane&15)
// so S^T lands with lane (lr,lg) holding P[q=lr][kv=ks*32+lg*8+i] — exactly
// the PV B-fragment layout. P never leaves the lane. Swapped PV gives o^T:
// softmax, rescale, and epilogue are fully in-lane.
template<bool MASK>
static __device__ __forceinline__ void attn_body(
    int kvb, int t0, int lr, int lg, int kvperm_base,
    const unsigned short* __restrict__ kbase,
    const unsigned short* __restrict__ vbase,
    const short8 (&qf)[4], f32x4 (&o)[8], float& mrow, float& lrow)
{
  const float SC = 0.03125f * 1.44269504f;  // C^-0.5 * log2(e)

  // --- K tile loads (16 x b128), permuted row order, batched
  short8 kf[4][4];
  #pragma unroll
  for (int nf = 0; nf < 4; ++nf) {
    const int kvrow = kvb + (nf >> 1) * 32 + (nf & 1) * 4 + kvperm_base;
    const unsigned short* kp = kbase + (size_t)kvrow * 128 + lg * 8;
    #pragma unroll
    for (int ks = 0; ks < 4; ++ks)
      kf[nf][ks] = *reinterpret_cast<const short8*>(kp + ks * 32);
  }

  // --- S^T = K_perm * Q^T  (C col = q row owned by lane)
  f32x4 sT[4];
  #pragma unroll
  for (int nf = 0; nf < 4; ++nf) {
    sT[nf] = (f32x4){0.f, 0.f, 0.f, 0.f};
    #pragma unroll
    for (int ks = 0; ks < 4; ++ks)
      sT[nf] = __builtin_amdgcn_mfma_f32_16x16x32_bf16(kf[nf][ks], qf[ks], sT[nf], 0, 0, 0);
  }

  // --- V tile loads (16 x b128): independent of softmax, issue now
  short8 vf[8][2];
  #pragma unroll
  for (int n = 0; n < 8; ++n) {
    const unsigned short* vp = vbase + (size_t)(n * 16 + lr) * 2048 + kvb + lg * 8;
    vf[n][0] = *reinterpret_cast<const short8*>(vp);
    vf[n][1] = *reinterpret_cast<const short8*>(vp + 32);
  }

  // --- softmax; lane's value (nf,j) is kv = kvb + (nf>>1)*32 + lg*8 + (nf&1)*4 + j
  float p[16];
  float pm = -1e30f;
  #pragma unroll
  for (int nf = 0; nf < 4; ++nf)
    #pragma unroll
    for (int j = 0; j < 4; ++j) {
      float s = sT[nf][j] * SC;
      if (MASK) {
        int kv = kvb + (nf >> 1) * 32 + lg * 8 + (nf & 1) * 4 + j;
        if (kv > t0 + lr) s = -1e30f;
      }
      p[nf * 4 + j] = s;
      pm = fmaxf(pm, s);
    }
  pm = fmaxf(pm, __shfl_xor(pm, 16));
  pm = fmaxf(pm, __shfl_xor(pm, 32));
  float mnew = fmaxf(mrow, pm);
  float fac = exp2f(mrow - mnew);
  mrow = mnew;
  float ps = 0.f;
  #pragma unroll
  for (int i = 0; i < 16; ++i) { p[i] = exp2f(p[i] - mnew); ps += p[i]; }
  ps += __shfl_xor(ps, 16);
  ps += __shfl_xor(ps, 32);
  lrow = lrow * fac + ps;
  #pragma unroll
  for (int n = 0; n < 8; ++n)
    #pragma unroll
    for (int j = 0; j < 4; ++j) o[n][j] *= fac;

  // --- pack P in-lane into PV B-fragments (already correctly distributed)
  #pragma unroll
  for (int ks = 0; ks < 2; ++ks) {
    union { unsigned int w[4]; short8 s; } cv;
    #pragma unroll
    for (int u = 0; u < 4; ++u) {
      int base = ks * 8 + u * 2;   // p indices ks*8+2u, ks*8+2u+1
      cv.w[u] = (unsigned)f2bf(p[base]) | ((unsigned)f2bf(p[base + 1]) << 16);
    }
    // o^T += V^T * P^T : A = V rows (h), B = P (col = q row lr)
    #pragma unroll
    for (int n = 0; n < 8; ++n)
      o[n] = __builtin_amdgcn_mfma_f32_16x16x32_bf16(vf[n][ks], cv.s, o[n], 0, 0, 0);
  }
}

__global__ __launch_bounds__(64) void attn_kernel(
    const unsigned short* __restrict__ q,   // [8][2048][128]
    const unsigned short* __restrict__ kb,  // [8][2048][128]
    const unsigned short* __restrict__ vt,  // [8][128][2048]
    float* __restrict__ out)                // [8][2048][128] f32
{
  const int lane = threadIdx.x;
  const int lr = lane & 15;                 // q-row owned by this lane
  const int lg = lane >> 4;                 // 0..3
  const int bid = blockIdx.x;
  const int b  = bid & 7;                   // batch -> XCD affinity
  const int qt = 127 - (bid >> 3);          // largest-first
  const int t0 = qt * 16;
  const int kvperm_base = (lr >> 2) * 8 + (lr & 3);  // per-lane K-row permutation

  // Q fragment (QK^T B-operand): lane holds q-row t0+lr
  short8 qf[4];
  const unsigned short* qp = q + ((size_t)(b * 2048 + t0 + lr)) * 128 + lg * 8;
  #pragma unroll
  for (int ks = 0; ks < 4; ++ks)
    qf[ks] = *reinterpret_cast<const short8*>(qp + ks * 32);

  f32x4 o[8];
  #pragma unroll
  for (int n = 0; n < 8; ++n) o[n] = (f32x4){0.f, 0.f, 0.f, 0.f};
  float mrow = -1e30f;
  float lrow = 0.f;

  const unsigned short* kbase = kb + (size_t)b * 2048 * 128;
  const unsigned short* vbase = vt + (size_t)b * 128 * 2048;

  const int kvend = (t0 >> 6) << 6;         // full mask-free 64-blocks
  for (int kvb = 0; kvb < kvend; kvb += 64)
    attn_body<false>(kvb, t0, lr, lg, kvperm_base, kbase, vbase, qf, o, mrow, lrow);
  attn_body<true>(kvend, t0, lr, lg, kvperm_base, kbase, vbase, qf, o, mrow, lrow);

  // epilogue: all in-lane (o^T col = q-row lr); contiguous float4 stores
  float rcp = 1.0f / lrow;
  float* op = out + ((size_t)(b * 2048) + t0 + lr) * 128;
  #pragma unroll
  for (int n = 0; n < 8; ++n) {
    float4 st;
    st.x = o[n][0] * rcp; st.y = o[n][1] * rcp;
    st.z = o[n][2] * rcp; st.w = o[n][3] * rcp;
    *reinterpret_cast<float4*>(op + n * 16 + lg * 4) = st;
  }
}

extern "C" void kernel_launch(void* const* d_in, const int* in_sizes, int n_in,
                              void* d_out, int out_size, void* d_ws, size_t ws_size,
                              hipStream_t stream) {
  const float* x  = (const float*)d_in[0];
  const float* Wk = (const float*)d_in[1];
  const float* Wq = (const float*)d_in[2];
  const float* Wv = (const float*)d_in[3];
  float* out = (float*)d_out;

  char* ws = (char*)d_ws;
  unsigned short* q  = (unsigned short*)(ws);                  // 4 MB
  unsigned short* kb = (unsigned short*)(ws + (4u  << 20));    // 4 MB
  unsigned short* vt = (unsigned short*)(ws + (8u  << 20));    // 4 MB
  unsigned short* Wt = (unsigned short*)(ws + (12u << 20));    // 768 KB

  wtrans_kernel<<<dim3(1536), dim3(256), 0, stream>>>(Wq, Wk, Wv, Wt);
  qkv_kernel<<<dim3(256), dim3(512), 0, stream>>>(x, Wt, q, kb, vt);
  attn_kernel<<<dim3(1024), dim3(64), 0, stream>>>(q, kb, vt, out);
}

// Round 5
// 115.723 us; speedup vs baseline: 1.9048x; 1.0970x over previous
//
#include <hip/hip_runtime.h>

// Head forward: q=x@Wq, k=x@Wk, v=x@Wv; out = softmax(causal(q k^T / 32)) @ v
// B=8 T=2048 C=1024 H=128. Inputs f32, output f32, internal bf16 MFMA.

typedef __attribute__((ext_vector_type(8))) short short8;
typedef __attribute__((ext_vector_type(4))) float f32x4;

#define LDS_PAD 40   // bf16 elems per LDS row for qkv staging

static __device__ __forceinline__ unsigned short f2bf(float f) {
  unsigned int u = __float_as_uint(f);
  u += 0x7FFF + ((u >> 16) & 1);      // round-to-nearest-even
  return (unsigned short)(u >> 16);
}

// ---------------- Kernel 0: Wt[w][n][k] = W_w[k][n] as bf16 (w: 0=Wq,1=Wk,2=Wv)
__global__ void wtrans_kernel(const float* __restrict__ Wq,
                              const float* __restrict__ Wk,
                              const float* __restrict__ Wv,
                              unsigned short* __restrict__ Wt) {
  int idx = blockIdx.x * blockDim.x + threadIdx.x;   // 0 .. 3*128*1024-1
  int w   = idx >> 17;
  int rem = idx & 131071;
  int n   = rem >> 10;
  int k   = rem & 1023;
  const float* W = (w == 0) ? Wq : (w == 1) ? Wk : Wv;
  Wt[idx] = f2bf(W[k * 128 + n]);
}

// ---------------- Kernel 1: fused QKV GEMM.  M=16384, K=1024, 3 x N=128.
__global__ __launch_bounds__(512) void qkv_kernel(
    const float* __restrict__ x,            // [16384][1024] f32
    const unsigned short* __restrict__ Wt,  // [3][128][1024] bf16
    unsigned short* __restrict__ q,         // [16384][128] bf16
    unsigned short* __restrict__ kb,        // [16384][128] bf16
    unsigned short* __restrict__ vt)        // [8][128][2048] bf16 (v transposed)
{
  __shared__ unsigned short xl[64 * LDS_PAD];
  const int tid  = threadIdx.x;
  const int lane = tid & 63;
  const int wave = tid >> 6;            // 0..7
  const int m0   = blockIdx.x * 64;
  const int lr   = lane & 15;           // A row-in-16 / B col-in-16
  const int lk   = (lane >> 4) * 8;     // k offset within 32

  f32x4 acc[4][3];
  for (int i = 0; i < 4; ++i)
    for (int w = 0; w < 3; ++w) acc[i][w] = (f32x4){0.f, 0.f, 0.f, 0.f};

  const int srow = tid >> 3;            // 0..63
  const int skc  = (tid & 7) * 4;       // 0..28
  const float* xsrc = x + (size_t)(m0 + srow) * 1024 + skc;

  for (int kt = 0; kt < 32; ++kt) {
    float4 v = *reinterpret_cast<const float4*>(xsrc + kt * 32);
    ushort4 u;
    u.x = f2bf(v.x); u.y = f2bf(v.y); u.z = f2bf(v.z); u.w = f2bf(v.w);
    *reinterpret_cast<ushort4*>(&xl[srow * LDS_PAD + skc]) = u;
    __syncthreads();

    short8 af[4];
    #pragma unroll
    for (int mf = 0; mf < 4; ++mf)
      af[mf] = *reinterpret_cast<const short8*>(&xl[(mf * 16 + lr) * LDS_PAD + lk]);

    #pragma unroll
    for (int w = 0; w < 3; ++w) {
      const unsigned short* bp =
          Wt + ((size_t)(w * 128 + wave * 16 + lr)) * 1024 + kt * 32 + lk;
      short8 bfr = *reinterpret_cast<const short8*>(bp);
      #pragma unroll
      for (int mf = 0; mf < 4; ++mf)
        acc[mf][w] = __builtin_amdgcn_mfma_f32_16x16x32_bf16(af[mf], bfr, acc[mf][w], 0, 0, 0);
    }
    __syncthreads();
  }

  const int h = wave * 16 + lr;
  const int b = m0 >> 11;
  #pragma unroll
  for (int mf = 0; mf < 4; ++mf) {
    int r0 = m0 + mf * 16 + (lane >> 4) * 4;
    #pragma unroll
    for (int j = 0; j < 4; ++j) {
      q [(size_t)(r0 + j) * 128 + h] = f2bf(acc[mf][0][j]);
      kb[(size_t)(r0 + j) * 128 + h] = f2bf(acc[mf][1][j]);
    }
    int t = r0 & 2047;
    ushort4 u;
    u.x = f2bf(acc[mf][2][0]); u.y = f2bf(acc[mf][2][1]);
    u.z = f2bf(acc[mf][2][2]); u.w = f2bf(acc[mf][2][3]);
    *reinterpret_cast<ushort4*>(vt + ((size_t)(b * 128 + h)) * 2048 + t) = u;
  }
}

// ---------------- Kernel 2: causal flash attention v5.
// 256 thr/block = 4 waves; wave w handles kv-blocks ib ≡ w (mod 4) of its
// q-tile (strided split-KV), each wave running the verified v4 body
// (permuted-K swapped QK^T, in-lane softmax, swapped PV -> o^T, no shuffles).
// Partials (o^T, m, l) merged in-block through LDS. 4 waves/SIMD co-resident.
template<bool MASK>
static __device__ __forceinline__ void attn_body(
    int kvb, int t0, int lr, int lg, int kvperm_base,
    const unsigned short* __restrict__ kbase,
    const unsigned short* __restrict__ vbase,
    const short8 (&qf)[4], f32x4 (&o)[8], float& mrow, float& lrow)
{
  const float SC = 0.03125f * 1.44269504f;  // C^-0.5 * log2(e)

  // --- K tile loads (16 x b128), permuted row order, batched
  short8 kf[4][4];
  #pragma unroll
  for (int nf = 0; nf < 4; ++nf) {
    const int kvrow = kvb + (nf >> 1) * 32 + (nf & 1) * 4 + kvperm_base;
    const unsigned short* kp = kbase + (size_t)kvrow * 128 + lg * 8;
    #pragma unroll
    for (int ks = 0; ks < 4; ++ks)
      kf[nf][ks] = *reinterpret_cast<const short8*>(kp + ks * 32);
  }

  // --- S^T = K_perm * Q^T  (C col = q row owned by lane)
  f32x4 sT[4];
  #pragma unroll
  for (int nf = 0; nf < 4; ++nf) {
    sT[nf] = (f32x4){0.f, 0.f, 0.f, 0.f};
    #pragma unroll
    for (int ks = 0; ks < 4; ++ks)
      sT[nf] = __builtin_amdgcn_mfma_f32_16x16x32_bf16(kf[nf][ks], qf[ks], sT[nf], 0, 0, 0);
  }

  // --- V tile loads (16 x b128): independent of softmax, issue now
  short8 vf[8][2];
  #pragma unroll
  for (int n = 0; n < 8; ++n) {
    const unsigned short* vp = vbase + (size_t)(n * 16 + lr) * 2048 + kvb + lg * 8;
    vf[n][0] = *reinterpret_cast<const short8*>(vp);
    vf[n][1] = *reinterpret_cast<const short8*>(vp + 32);
  }

  // --- softmax; lane's value (nf,j) is kv = kvb + (nf>>1)*32 + lg*8 + (nf&1)*4 + j
  float p[16];
  float pm = -1e30f;
  #pragma unroll
  for (int nf = 0; nf < 4; ++nf)
    #pragma unroll
    for (int j = 0; j < 4; ++j) {
      float s = sT[nf][j] * SC;
      if (MASK) {
        int kv = kvb + (nf >> 1) * 32 + lg * 8 + (nf & 1) * 4 + j;
        if (kv > t0 + lr) s = -1e30f;
      }
      p[nf * 4 + j] = s;
      pm = fmaxf(pm, s);
    }
  pm = fmaxf(pm, __shfl_xor(pm, 16));
  pm = fmaxf(pm, __shfl_xor(pm, 32));
  float mnew = fmaxf(mrow, pm);
  float fac = exp2f(mrow - mnew);
  mrow = mnew;
  float ps = 0.f;
  #pragma unroll
  for (int i = 0; i < 16; ++i) { p[i] = exp2f(p[i] - mnew); ps += p[i]; }
  ps += __shfl_xor(ps, 16);
  ps += __shfl_xor(ps, 32);
  lrow = lrow * fac + ps;
  #pragma unroll
  for (int n = 0; n < 8; ++n)
    #pragma unroll
    for (int j = 0; j < 4; ++j) o[n][j] *= fac;

  // --- pack P in-lane into PV B-fragments (already correctly distributed)
  #pragma unroll
  for (int ks = 0; ks < 2; ++ks) {
    union { unsigned int w[4]; short8 s; } cv;
    #pragma unroll
    for (int u = 0; u < 4; ++u) {
      int base = ks * 8 + u * 2;   // p indices ks*8+2u, ks*8+2u+1
      cv.w[u] = (unsigned)f2bf(p[base]) | ((unsigned)f2bf(p[base + 1]) << 16);
    }
    // o^T += V^T * P^T : A = V rows (h), B = P (col = q row lr)
    #pragma unroll
    for (int n = 0; n < 8; ++n)
      o[n] = __builtin_amdgcn_mfma_f32_16x16x32_bf16(vf[n][ks], cv.s, o[n], 0, 0, 0);
  }
}

__global__ __launch_bounds__(256) void attn_kernel(
    const unsigned short* __restrict__ q,   // [8][2048][128]
    const unsigned short* __restrict__ kb,  // [8][2048][128]
    const unsigned short* __restrict__ vt,  // [8][128][2048]
    float* __restrict__ out)                // [8][2048][128] f32
{
  __shared__ float ol[4][16][132];   // per-wave o^T partials (padded stride)
  __shared__ float ml[4][16];
  __shared__ float ll[4][16];

  const int tid  = threadIdx.x;
  const int lane = tid & 63;
  const int wv   = tid >> 6;                // 0..3: kv-split wave id
  const int lr = lane & 15;                 // q-row owned by this lane
  const int lg = lane >> 4;                 // 0..3
  const int bid = blockIdx.x;
  const int b  = bid & 7;                   // batch -> XCD affinity
  const int qt = 127 - (bid >> 3);          // largest-first
  const int t0 = qt * 16;
  const int kvperm_base = (lr >> 2) * 8 + (lr & 3);  // per-lane K-row permutation

  // Q fragment (QK^T B-operand): lane holds q-row t0+lr
  short8 qf[4];
  const unsigned short* qp = q + ((size_t)(b * 2048 + t0 + lr)) * 128 + lg * 8;
  #pragma unroll
  for (int ks = 0; ks < 4; ++ks)
    qf[ks] = *reinterpret_cast<const short8*>(qp + ks * 32);

  f32x4 o[8];
  #pragma unroll
  for (int n = 0; n < 8; ++n) o[n] = (f32x4){0.f, 0.f, 0.f, 0.f};
  float mrow = -1e30f;
  float lrow = 0.f;

  const unsigned short* kbase = kb + (size_t)b * 2048 * 128;
  const unsigned short* vbase = vt + (size_t)b * 128 * 2048;

  const int nb = ((t0 >> 6) << 6) / 64 + 1;   // kv-blocks incl. diagonal
  for (int ib = wv; ib < nb - 1; ib += 4)
    attn_body<false>(ib * 64, t0, lr, lg, kvperm_base, kbase, vbase, qf, o, mrow, lrow);
  if (((nb - 1) & 3) == wv)
    attn_body<true>((nb - 1) * 64, t0, lr, lg, kvperm_base, kbase, vbase, qf, o, mrow, lrow);

  // --- write partials to LDS
  #pragma unroll
  for (int n = 0; n < 8; ++n) {
    float4 st;
    st.x = o[n][0]; st.y = o[n][1]; st.z = o[n][2]; st.w = o[n][3];
    *reinterpret_cast<float4*>(&ol[wv][lr][n * 16 + lg * 4]) = st;
  }
  if (lg == 0) { ml[wv][lr] = mrow; ll[wv][lr] = lrow; }
  __syncthreads();

  // --- merge 4 partials; thread handles row r, 8 cols
  const int r  = tid >> 4;           // 0..15
  const int c0 = (tid & 15) * 8;     // 0..120
  float m0 = ml[0][r], m1 = ml[1][r], m2 = ml[2][r], m3 = ml[3][r];
  float M  = fmaxf(fmaxf(m0, m1), fmaxf(m2, m3));
  float f0 = exp2f(m0 - M), f1 = exp2f(m1 - M), f2 = exp2f(m2 - M), f3 = exp2f(m3 - M);
  float rcp = 1.0f / (f0 * ll[0][r] + f1 * ll[1][r] + f2 * ll[2][r] + f3 * ll[3][r]);

  float* op = out + ((size_t)(b * 2048) + t0 + r) * 128 + c0;
  #pragma unroll
  for (int h = 0; h < 8; h += 4) {
    float4 a0 = *reinterpret_cast<const float4*>(&ol[0][r][c0 + h]);
    float4 a1 = *reinterpret_cast<const float4*>(&ol[1][r][c0 + h]);
    float4 a2 = *reinterpret_cast<const float4*>(&ol[2][r][c0 + h]);
    float4 a3 = *reinterpret_cast<const float4*>(&ol[3][r][c0 + h]);
    float4 st;
    st.x = (f0 * a0.x + f1 * a1.x + f2 * a2.x + f3 * a3.x) * rcp;
    st.y = (f0 * a0.y + f1 * a1.y + f2 * a2.y + f3 * a3.y) * rcp;
    st.z = (f0 * a0.z + f1 * a1.z + f2 * a2.z + f3 * a3.z) * rcp;
    st.w = (f0 * a0.w + f1 * a1.w + f2 * a2.w + f3 * a3.w) * rcp;
    *reinterpret_cast<float4*>(op + h) = st;
  }
}

extern "C" void kernel_launch(void* const* d_in, const int* in_sizes, int n_in,
                              void* d_out, int out_size, void* d_ws, size_t ws_size,
                              hipStream_t stream) {
  const float* x  = (const float*)d_in[0];
  const float* Wk = (const float*)d_in[1];
  const float* Wq = (const float*)d_in[2];
  const float* Wv = (const float*)d_in[3];
  float* out = (float*)d_out;

  char* ws = (char*)d_ws;
  unsigned short* q  = (unsigned short*)(ws);                  // 4 MB
  unsigned short* kb = (unsigned short*)(ws + (4u  << 20));    // 4 MB
  unsigned short* vt = (unsigned short*)(ws + (8u  << 20));    // 4 MB
  unsigned short* Wt = (unsigned short*)(ws + (12u << 20));    // 768 KB

  wtrans_kernel<<<dim3(1536), dim3(256), 0, stream>>>(Wq, Wk, Wv, Wt);
  qkv_kernel<<<dim3(256), dim3(512), 0, stream>>>(x, Wt, q, kb, vt);
  attn_kernel<<<dim3(1024), dim3(256), 0, stream>>>(q, kb, vt, out);
}

// Round 6
// 109.223 us; speedup vs baseline: 2.0182x; 1.0595x over previous
//
#include <hip/hip_runtime.h>

// Head forward: q=x@Wq, k=x@Wk, v=x@Wv; out = softmax(causal(q k^T / 32)) @ v
// B=8 T=2048 C=1024 H=128. Inputs f32, output f32, internal bf16 MFMA.

typedef __attribute__((ext_vector_type(8))) short short8;
typedef __attribute__((ext_vector_type(4))) float f32x4;

#define LDS_PAD 40   // bf16 elems per LDS row for qkv staging

static __device__ __forceinline__ unsigned short f2bf(float f) {
  unsigned int u = __float_as_uint(f);
  u += 0x7FFF + ((u >> 16) & 1);      // round-to-nearest-even
  return (unsigned short)(u >> 16);
}

// ---------------- Kernel 0: Wt[w][n][k] = W_w[k][n] as bf16 (w: 0=Wq,1=Wk,2=Wv)
__global__ void wtrans_kernel(const float* __restrict__ Wq,
                              const float* __restrict__ Wk,
                              const float* __restrict__ Wv,
                              unsigned short* __restrict__ Wt) {
  int idx = blockIdx.x * blockDim.x + threadIdx.x;   // 0 .. 3*128*1024-1
  int w   = idx >> 17;
  int rem = idx & 131071;
  int n   = rem >> 10;
  int k   = rem & 1023;
  const float* W = (w == 0) ? Wq : (w == 1) ? Wk : Wv;
  Wt[idx] = f2bf(W[k * 128 + n]);
}

// ---------------- Kernel 1: fused QKV GEMM.  M=16384, K=1024, 3 x N=128.
// Double-buffered LDS staging + register prefetch of next x-tile (HBM) and
// next B-fragments (L2): loads for kt+1 issue before kt's MFMAs, one barrier
// per K-step. 8 waves; wave owns 16 cols of each of the 3 weights.
__global__ __launch_bounds__(512, 2) void qkv_kernel(
    const float* __restrict__ x,            // [16384][1024] f32
    const unsigned short* __restrict__ Wt,  // [3][128][1024] bf16
    unsigned short* __restrict__ q,         // [16384][128] bf16
    unsigned short* __restrict__ kb,        // [16384][128] bf16
    unsigned short* __restrict__ vt)        // [8][128][2048] bf16 (v transposed)
{
  __shared__ unsigned short xl[2][64 * LDS_PAD];
  const int tid  = threadIdx.x;
  const int lane = tid & 63;
  const int wave = tid >> 6;            // 0..7
  const int m0   = blockIdx.x * 64;
  const int lr   = lane & 15;           // A row-in-16 / B col-in-16
  const int lk   = (lane >> 4) * 8;     // k offset within 32

  f32x4 acc[4][3];
  for (int i = 0; i < 4; ++i)
    for (int w = 0; w < 3; ++w) acc[i][w] = (f32x4){0.f, 0.f, 0.f, 0.f};

  const int srow = tid >> 3;            // 0..63
  const int skc  = (tid & 7) * 4;       // 0..28
  const float* xsrc = x + (size_t)(m0 + srow) * 1024 + skc;
  const unsigned short* bbase = Wt + ((size_t)(wave * 16 + lr)) * 1024 + lk;

  // prologue: stage tile 0, prefetch B frags for kt=0
  float4 xv = *reinterpret_cast<const float4*>(xsrc);
  short8 bcur[3];
  #pragma unroll
  for (int w = 0; w < 3; ++w)
    bcur[w] = *reinterpret_cast<const short8*>(bbase + w * 131072);
  {
    ushort4 u;
    u.x = f2bf(xv.x); u.y = f2bf(xv.y); u.z = f2bf(xv.z); u.w = f2bf(xv.w);
    *reinterpret_cast<ushort4*>(&xl[0][srow * LDS_PAD + skc]) = u;
  }
  __syncthreads();

  for (int kt = 0; kt < 32; ++kt) {
    const int cur = kt & 1;
    // prefetch next x tile (HBM) + next B frags (L2) — in flight during MFMAs
    float4 xn;
    short8 bnxt[3];
    if (kt < 31) {
      xn = *reinterpret_cast<const float4*>(xsrc + (kt + 1) * 32);
      #pragma unroll
      for (int w = 0; w < 3; ++w)
        bnxt[w] = *reinterpret_cast<const short8*>(bbase + w * 131072 + (kt + 1) * 32);
    }

    short8 af[4];
    #pragma unroll
    for (int mf = 0; mf < 4; ++mf)
      af[mf] = *reinterpret_cast<const short8*>(&xl[cur][(mf * 16 + lr) * LDS_PAD + lk]);

    #pragma unroll
    for (int w = 0; w < 3; ++w)
      #pragma unroll
      for (int mf = 0; mf < 4; ++mf)
        acc[mf][w] = __builtin_amdgcn_mfma_f32_16x16x32_bf16(af[mf], bcur[w], acc[mf][w], 0, 0, 0);

    if (kt < 31) {
      ushort4 u;
      u.x = f2bf(xn.x); u.y = f2bf(xn.y); u.z = f2bf(xn.z); u.w = f2bf(xn.w);
      *reinterpret_cast<ushort4*>(&xl[cur ^ 1][srow * LDS_PAD + skc]) = u;
      bcur[0] = bnxt[0]; bcur[1] = bnxt[1]; bcur[2] = bnxt[2];
      __syncthreads();
    }
  }

  const int h = wave * 16 + lr;
  const int b = m0 >> 11;
  #pragma unroll
  for (int mf = 0; mf < 4; ++mf) {
    int r0 = m0 + mf * 16 + (lane >> 4) * 4;
    #pragma unroll
    for (int j = 0; j < 4; ++j) {
      q [(size_t)(r0 + j) * 128 + h] = f2bf(acc[mf][0][j]);
      kb[(size_t)(r0 + j) * 128 + h] = f2bf(acc[mf][1][j]);
    }
    int t = r0 & 2047;
    ushort4 u;
    u.x = f2bf(acc[mf][2][0]); u.y = f2bf(acc[mf][2][1]);
    u.z = f2bf(acc[mf][2][2]); u.w = f2bf(acc[mf][2][3]);
    *reinterpret_cast<ushort4*>(vt + ((size_t)(b * 128 + h)) * 2048 + t) = u;
  }
}

// ---------------- Kernel 2: causal flash attention v6.
// = v5 split-KV structure, but with enough VGPR (launch_bounds 256,2) to keep
// all 32 of an iteration's 16B loads in flight, and V loads hoisted above the
// QK MFMAs so K+V batch into one L2 round-trip per iteration.
template<bool MASK>
static __device__ __forceinline__ void attn_body(
    int kvb, int t0, int lr, int lg, int kvperm_base,
    const unsigned short* __restrict__ kbase,
    const unsigned short* __restrict__ vbase,
    const short8 (&qf)[4], f32x4 (&o)[8], float& mrow, float& lrow)
{
  const float SC = 0.03125f * 1.44269504f;  // C^-0.5 * log2(e)

  // --- K tile loads (16 x b128), permuted row order, batched
  short8 kf[4][4];
  #pragma unroll
  for (int nf = 0; nf < 4; ++nf) {
    const int kvrow = kvb + (nf >> 1) * 32 + (nf & 1) * 4 + kvperm_base;
    const unsigned short* kp = kbase + (size_t)kvrow * 128 + lg * 8;
    #pragma unroll
    for (int ks = 0; ks < 4; ++ks)
      kf[nf][ks] = *reinterpret_cast<const short8*>(kp + ks * 32);
  }
  // --- V tile loads (16 x b128): hoisted, batch with K into one round-trip
  short8 vf[8][2];
  #pragma unroll
  for (int n = 0; n < 8; ++n) {
    const unsigned short* vp = vbase + (size_t)(n * 16 + lr) * 2048 + kvb + lg * 8;
    vf[n][0] = *reinterpret_cast<const short8*>(vp);
    vf[n][1] = *reinterpret_cast<const short8*>(vp + 32);
  }

  // --- S^T = K_perm * Q^T  (C col = q row owned by lane)
  f32x4 sT[4];
  #pragma unroll
  for (int nf = 0; nf < 4; ++nf) {
    sT[nf] = (f32x4){0.f, 0.f, 0.f, 0.f};
    #pragma unroll
    for (int ks = 0; ks < 4; ++ks)
      sT[nf] = __builtin_amdgcn_mfma_f32_16x16x32_bf16(kf[nf][ks], qf[ks], sT[nf], 0, 0, 0);
  }

  // --- softmax; lane's value (nf,j) is kv = kvb + (nf>>1)*32 + lg*8 + (nf&1)*4 + j
  float p[16];
  float pm = -1e30f;
  #pragma unroll
  for (int nf = 0; nf < 4; ++nf)
    #pragma unroll
    for (int j = 0; j < 4; ++j) {
      float s = sT[nf][j] * SC;
      if (MASK) {
        int kv = kvb + (nf >> 1) * 32 + lg * 8 + (nf & 1) * 4 + j;
        if (kv > t0 + lr) s = -1e30f;
      }
      p[nf * 4 + j] = s;
      pm = fmaxf(pm, s);
    }
  pm = fmaxf(pm, __shfl_xor(pm, 16));
  pm = fmaxf(pm, __shfl_xor(pm, 32));
  float mnew = fmaxf(mrow, pm);
  float fac = exp2f(mrow - mnew);
  mrow = mnew;
  float ps = 0.f;
  #pragma unroll
  for (int i = 0; i < 16; ++i) { p[i] = exp2f(p[i] - mnew); ps += p[i]; }
  ps += __shfl_xor(ps, 16);
  ps += __shfl_xor(ps, 32);
  lrow = lrow * fac + ps;
  #pragma unroll
  for (int n = 0; n < 8; ++n)
    #pragma unroll
    for (int j = 0; j < 4; ++j) o[n][j] *= fac;

  // --- pack P in-lane into PV B-fragments (already correctly distributed)
  #pragma unroll
  for (int ks = 0; ks < 2; ++ks) {
    union { unsigned int w[4]; short8 s; } cv;
    #pragma unroll
    for (int u = 0; u < 4; ++u) {
      int base = ks * 8 + u * 2;   // p indices ks*8+2u, ks*8+2u+1
      cv.w[u] = (unsigned)f2bf(p[base]) | ((unsigned)f2bf(p[base + 1]) << 16);
    }
    // o^T += V^T * P^T : A = V rows (h), B = P (col = q row lr)
    #pragma unroll
    for (int n = 0; n < 8; ++n)
      o[n] = __builtin_amdgcn_mfma_f32_16x16x32_bf16(vf[n][ks], cv.s, o[n], 0, 0, 0);
  }
}

__global__ __launch_bounds__(256, 2) void attn_kernel(
    const unsigned short* __restrict__ q,   // [8][2048][128]
    const unsigned short* __restrict__ kb,  // [8][2048][128]
    const unsigned short* __restrict__ vt,  // [8][128][2048]
    float* __restrict__ out)                // [8][2048][128] f32
{
  __shared__ float ol[4][16][132];   // per-wave o^T partials (padded stride)
  __shared__ float ml[4][16];
  __shared__ float ll[4][16];

  const int tid  = threadIdx.x;
  const int lane = tid & 63;
  const int wv   = tid >> 6;                // 0..3: kv-split wave id
  const int lr = lane & 15;                 // q-row owned by this lane
  const int lg = lane >> 4;                 // 0..3
  const int bid = blockIdx.x;
  const int b  = bid & 7;                   // batch -> XCD affinity
  const int qt = 127 - (bid >> 3);          // largest-first
  const int t0 = qt * 16;
  const int kvperm_base = (lr >> 2) * 8 + (lr & 3);  // per-lane K-row permutation

  // Q fragment (QK^T B-operand): lane holds q-row t0+lr
  short8 qf[4];
  const unsigned short* qp = q + ((size_t)(b * 2048 + t0 + lr)) * 128 + lg * 8;
  #pragma unroll
  for (int ks = 0; ks < 4; ++ks)
    qf[ks] = *reinterpret_cast<const short8*>(qp + ks * 32);

  f32x4 o[8];
  #pragma unroll
  for (int n = 0; n < 8; ++n) o[n] = (f32x4){0.f, 0.f, 0.f, 0.f};
  float mrow = -1e30f;
  float lrow = 0.f;

  const unsigned short* kbase = kb + (size_t)b * 2048 * 128;
  const unsigned short* vbase = vt + (size_t)b * 128 * 2048;

  const int nb = ((t0 >> 6) << 6) / 64 + 1;   // kv-blocks incl. diagonal
  for (int ib = wv; ib < nb - 1; ib += 4)
    attn_body<false>(ib * 64, t0, lr, lg, kvperm_base, kbase, vbase, qf, o, mrow, lrow);
  if (((nb - 1) & 3) == wv)
    attn_body<true>((nb - 1) * 64, t0, lr, lg, kvperm_base, kbase, vbase, qf, o, mrow, lrow);

  // --- write partials to LDS
  #pragma unroll
  for (int n = 0; n < 8; ++n) {
    float4 st;
    st.x = o[n][0]; st.y = o[n][1]; st.z = o[n][2]; st.w = o[n][3];
    *reinterpret_cast<float4*>(&ol[wv][lr][n * 16 + lg * 4]) = st;
  }
  if (lg == 0) { ml[wv][lr] = mrow; ll[wv][lr] = lrow; }
  __syncthreads();

  // --- merge 4 partials; thread handles row r, 8 cols
  const int r  = tid >> 4;           // 0..15
  const int c0 = (tid & 15) * 8;     // 0..120
  float m0 = ml[0][r], m1 = ml[1][r], m2 = ml[2][r], m3 = ml[3][r];
  float M  = fmaxf(fmaxf(m0, m1), fmaxf(m2, m3));
  float f0 = exp2f(m0 - M), f1 = exp2f(m1 - M), f2 = exp2f(m2 - M), f3 = exp2f(m3 - M);
  float rcp = 1.0f / (f0 * ll[0][r] + f1 * ll[1][r] + f2 * ll[2][r] + f3 * ll[3][r]);

  float* op = out + ((size_t)(b * 2048) + t0 + r) * 128 + c0;
  #pragma unroll
  for (int h = 0; h < 8; h += 4) {
    float4 a0 = *reinterpret_cast<const float4*>(&ol[0][r][c0 + h]);
    float4 a1 = *reinterpret_cast<const float4*>(&ol[1][r][c0 + h]);
    float4 a2 = *reinterpret_cast<const float4*>(&ol[2][r][c0 + h]);
    float4 a3 = *reinterpret_cast<const float4*>(&ol[3][r][c0 + h]);
    float4 st;
    st.x = (f0 * a0.x + f1 * a1.x + f2 * a2.x + f3 * a3.x) * rcp;
    st.y = (f0 * a0.y + f1 * a1.y + f2 * a2.y + f3 * a3.y) * rcp;
    st.z = (f0 * a0.z + f1 * a1.z + f2 * a2.z + f3 * a3.z) * rcp;
    st.w = (f0 * a0.w + f1 * a1.w + f2 * a2.w + f3 * a3.w) * rcp;
    *reinterpret_cast<float4*>(op + h) = st;
  }
}

extern "C" void kernel_launch(void* const* d_in, const int* in_sizes, int n_in,
                              void* d_out, int out_size, void* d_ws, size_t ws_size,
                              hipStream_t stream) {
  const float* x  = (const float*)d_in[0];
  const float* Wk = (const float*)d_in[1];
  const float* Wq = (const float*)d_in[2];
  const float* Wv = (const float*)d_in[3];
  float* out = (float*)d_out;

  char* ws = (char*)d_ws;
  unsigned short* q  = (unsigned short*)(ws);                  // 4 MB
  unsigned short* kb = (unsigned short*)(ws + (4u  << 20));    // 4 MB
  unsigned short* vt = (unsigned short*)(ws + (8u  << 20));    // 4 MB
  unsigned short* Wt = (unsigned short*)(ws + (12u << 20));    // 768 KB

  wtrans_kernel<<<dim3(1536), dim3(256), 0, stream>>>(Wq, Wk, Wv, Wt);
  qkv_kernel<<<dim3(256), dim3(512), 0, stream>>>(x, Wt, q, kb, vt);
  attn_kernel<<<dim3(1024), dim3(256), 0, stream>>>(q, kb, vt, out);
}

// Round 7
// 108.260 us; speedup vs baseline: 2.0361x; 1.0089x over previous
//
#include <hip/hip_runtime.h>

// Head forward: q=x@Wq, k=x@Wk, v=x@Wv; out = softmax(causal(q k^T / 32)) @ v
// B=8 T=2048 C=1024 H=128. Inputs f32, output f32, internal bf16 MFMA.

typedef __attribute__((ext_vector_type(8))) short short8;
typedef __attribute__((ext_vector_type(4))) float f32x4;

typedef const __attribute__((address_space(1))) unsigned int* gas_u32p;
typedef __attribute__((address_space(3))) unsigned int* las_u32p;

#define LDS_PAD 40   // bf16 elems per LDS row for qkv staging

static __device__ __forceinline__ unsigned short f2bf(float f) {
  unsigned int u = __float_as_uint(f);
  u += 0x7FFF + ((u >> 16) & 1);      // round-to-nearest-even
  return (unsigned short)(u >> 16);
}

// ---------------- Kernel 0: Wt[w][n][k] = W_w[k][n] as bf16 (w: 0=Wq,1=Wk,2=Wv)
__global__ void wtrans_kernel(const float* __restrict__ Wq,
                              const float* __restrict__ Wk,
                              const float* __restrict__ Wv,
                              unsigned short* __restrict__ Wt) {
  int idx = blockIdx.x * blockDim.x + threadIdx.x;   // 0 .. 3*128*1024-1
  int w   = idx >> 17;
  int rem = idx & 131071;
  int n   = rem >> 10;
  int k   = rem & 1023;
  const float* W = (w == 0) ? Wq : (w == 1) ? Wk : Wv;
  Wt[idx] = f2bf(W[k * 128 + n]);
}

// ---------------- Kernel 1: fused QKV GEMM.  M=16384, K=1024, 3 x N=128.
// Double-buffered LDS staging + register prefetch. NOTE: kb and vt are
// written with a 16B-chunk XOR swizzle (kb: h^((r&7)<<3); vt: t^((h&7)<<3))
// so the attention kernel can global_load_lds them LINEARLY and read
// fragments bank-conflict-free with the same XOR.
__global__ __launch_bounds__(512, 2) void qkv_kernel(
    const float* __restrict__ x,            // [16384][1024] f32
    const unsigned short* __restrict__ Wt,  // [3][128][1024] bf16
    unsigned short* __restrict__ q,         // [16384][128] bf16 (unswizzled)
    unsigned short* __restrict__ kb,        // [16384][128] bf16 (swizzled)
    unsigned short* __restrict__ vt)        // [8][128][2048] bf16 (v^T, swizzled)
{
  __shared__ unsigned short xl[2][64 * LDS_PAD];
  const int tid  = threadIdx.x;
  const int lane = tid & 63;
  const int wave = tid >> 6;            // 0..7
  const int m0   = blockIdx.x * 64;
  const int lr   = lane & 15;           // A row-in-16 / B col-in-16
  const int lk   = (lane >> 4) * 8;     // k offset within 32

  f32x4 acc[4][3];
  for (int i = 0; i < 4; ++i)
    for (int w = 0; w < 3; ++w) acc[i][w] = (f32x4){0.f, 0.f, 0.f, 0.f};

  const int srow = tid >> 3;            // 0..63
  const int skc  = (tid & 7) * 4;       // 0..28
  const float* xsrc = x + (size_t)(m0 + srow) * 1024 + skc;
  const unsigned short* bbase = Wt + ((size_t)(wave * 16 + lr)) * 1024 + lk;

  // prologue: stage tile 0, prefetch B frags for kt=0
  float4 xv = *reinterpret_cast<const float4*>(xsrc);
  short8 bcur[3];
  #pragma unroll
  for (int w = 0; w < 3; ++w)
    bcur[w] = *reinterpret_cast<const short8*>(bbase + w * 131072);
  {
    ushort4 u;
    u.x = f2bf(xv.x); u.y = f2bf(xv.y); u.z = f2bf(xv.z); u.w = f2bf(xv.w);
    *reinterpret_cast<ushort4*>(&xl[0][srow * LDS_PAD + skc]) = u;
  }
  __syncthreads();

  for (int kt = 0; kt < 32; ++kt) {
    const int cur = kt & 1;
    float4 xn;
    short8 bnxt[3];
    if (kt < 31) {
      xn = *reinterpret_cast<const float4*>(xsrc + (kt + 1) * 32);
      #pragma unroll
      for (int w = 0; w < 3; ++w)
        bnxt[w] = *reinterpret_cast<const short8*>(bbase + w * 131072 + (kt + 1) * 32);
    }

    short8 af[4];
    #pragma unroll
    for (int mf = 0; mf < 4; ++mf)
      af[mf] = *reinterpret_cast<const short8*>(&xl[cur][(mf * 16 + lr) * LDS_PAD + lk]);

    #pragma unroll
    for (int w = 0; w < 3; ++w)
      #pragma unroll
      for (int mf = 0; mf < 4; ++mf)
        acc[mf][w] = __builtin_amdgcn_mfma_f32_16x16x32_bf16(af[mf], bcur[w], acc[mf][w], 0, 0, 0);

    if (kt < 31) {
      ushort4 u;
      u.x = f2bf(xn.x); u.y = f2bf(xn.y); u.z = f2bf(xn.z); u.w = f2bf(xn.w);
      *reinterpret_cast<ushort4*>(&xl[cur ^ 1][srow * LDS_PAD + skc]) = u;
      bcur[0] = bnxt[0]; bcur[1] = bnxt[1]; bcur[2] = bnxt[2];
      __syncthreads();
    }
  }

  const int h = wave * 16 + lr;
  const int b = m0 >> 11;
  #pragma unroll
  for (int mf = 0; mf < 4; ++mf) {
    int r0 = m0 + mf * 16 + (lane >> 4) * 4;
    #pragma unroll
    for (int j = 0; j < 4; ++j) {
      int r = r0 + j;
      q [(size_t)r * 128 + h] = f2bf(acc[mf][0][j]);
      kb[(size_t)r * 128 + (h ^ ((r & 7) << 3))] = f2bf(acc[mf][1][j]);  // swizzled
    }
    int t = r0 & 2047;
    ushort4 u;
    u.x = f2bf(acc[mf][2][0]); u.y = f2bf(acc[mf][2][1]);
    u.z = f2bf(acc[mf][2][2]); u.w = f2bf(acc[mf][2][3]);
    *reinterpret_cast<ushort4*>(
        vt + ((size_t)(b * 128 + h)) * 2048 + (t ^ ((h & 7) << 3))) = u;  // swizzled
  }
}

// ---------------- Kernel 2: causal flash attention v7.
// 128 blocks (16 pairs x 8 batches) x 256 thr (4 waves). Block owns two
// 64-row q-tiles (pair p: tiles 31-p and p) -> uniform 33 kv-iterations.
// Per iteration: K(16KB)+V(16KB) staged ONCE per block into double-buffered
// LDS via global_load_lds (linear; global layout pre-swizzled), shared by
// all 4 waves. Each wave runs the verified 16-row body: permuted-K swapped
// QK^T, in-lane softmax, in-lane P, swapped PV -> o^T.
template<bool MASK>
static __device__ __forceinline__ void attn_body(
    int kvb, int myrow, int lr, int lg, int kvperm_base,
    const unsigned short* __restrict__ klc,   // LDS K tile [64][128] swizzled
    const unsigned short* __restrict__ vlc,   // LDS V tile [128][64] swizzled
    const short8 (&qf)[4], f32x4 (&o)[8], float& mrow, float& lrow)
{
  const float SC = 0.03125f * 1.44269504f;  // C^-0.5 * log2(e)

  // --- K fragments from LDS (XOR de-swizzle; 2-way conflicts only)
  short8 kf[4][4];
  const char* kbuf = (const char*)klc;
  #pragma unroll
  for (int nf = 0; nf < 4; ++nf) {
    const int rr = (nf >> 1) * 32 + (nf & 1) * 4 + kvperm_base;
    const int sw = (rr & 7) << 4;
    #pragma unroll
    for (int ks = 0; ks < 4; ++ks)
      kf[nf][ks] = *reinterpret_cast<const short8*>(kbuf + rr * 256 + ((lg * 16 + ks * 64) ^ sw));
  }
  // --- V fragments from LDS
  short8 vf[8][2];
  const char* vbuf = (const char*)vlc;
  #pragma unroll
  for (int n = 0; n < 8; ++n) {
    const int h = n * 16 + lr;
    const int sw = (h & 7) << 4;
    const char* vrow = vbuf + h * 128;
    vf[n][0] = *reinterpret_cast<const short8*>(vrow + ((lg * 16) ^ sw));
    vf[n][1] = *reinterpret_cast<const short8*>(vrow + ((lg * 16 + 64) ^ sw));
  }

  // --- S^T = K_perm * Q^T  (C col = q row owned by lane)
  f32x4 sT[4];
  #pragma unroll
  for (int nf = 0; nf < 4; ++nf) {
    sT[nf] = (f32x4){0.f, 0.f, 0.f, 0.f};
    #pragma unroll
    for (int ks = 0; ks < 4; ++ks)
      sT[nf] = __builtin_amdgcn_mfma_f32_16x16x32_bf16(kf[nf][ks], qf[ks], sT[nf], 0, 0, 0);
  }

  // --- softmax; lane's value (nf,j) is kv = kvb + (nf>>1)*32 + lg*8 + (nf&1)*4 + j
  float p[16];
  float pm = -1e30f;
  #pragma unroll
  for (int nf = 0; nf < 4; ++nf)
    #pragma unroll
    for (int j = 0; j < 4; ++j) {
      float s = sT[nf][j] * SC;
      if (MASK) {
        int kv = kvb + (nf >> 1) * 32 + lg * 8 + (nf & 1) * 4 + j;
        if (kv > myrow) s = -1e30f;
      }
      p[nf * 4 + j] = s;
      pm = fmaxf(pm, s);
    }
  pm = fmaxf(pm, __shfl_xor(pm, 16));
  pm = fmaxf(pm, __shfl_xor(pm, 32));
  float mnew = fmaxf(mrow, pm);
  float fac = exp2f(mrow - mnew);
  mrow = mnew;
  float ps = 0.f;
  #pragma unroll
  for (int i = 0; i < 16; ++i) { p[i] = exp2f(p[i] - mnew); ps += p[i]; }
  ps += __shfl_xor(ps, 16);
  ps += __shfl_xor(ps, 32);
  lrow = lrow * fac + ps;
  #pragma unroll
  for (int n = 0; n < 8; ++n)
    #pragma unroll
    for (int j = 0; j < 4; ++j) o[n][j] *= fac;

  // --- pack P in-lane into PV B-fragments (already correctly distributed)
  #pragma unroll
  for (int ks = 0; ks < 2; ++ks) {
    union { unsigned int w[4]; short8 s; } cv;
    #pragma unroll
    for (int u = 0; u < 4; ++u) {
      int base = ks * 8 + u * 2;
      cv.w[u] = (unsigned)f2bf(p[base]) | ((unsigned)f2bf(p[base + 1]) << 16);
    }
    #pragma unroll
    for (int n = 0; n < 8; ++n)
      o[n] = __builtin_amdgcn_mfma_f32_16x16x32_bf16(vf[n][ks], cv.s, o[n], 0, 0, 0);
  }
}

__global__ __launch_bounds__(256) void attn_kernel(
    const unsigned short* __restrict__ q,   // [8][2048][128] (unswizzled)
    const unsigned short* __restrict__ kb,  // [8][2048][128] (swizzled)
    const unsigned short* __restrict__ vt,  // [8][128][2048] (swizzled)
    float* __restrict__ out)                // [8][2048][128] f32
{
  __shared__ unsigned short kl[2][64 * 128];   // 2 x 16KB K tiles
  __shared__ unsigned short vl[2][128 * 64];   // 2 x 16KB V tiles

  const int tid  = threadIdx.x;
  const int lane = tid & 63;
  const int wv   = tid >> 6;                // wave id 0..3 (owns 16 q-rows)
  const int lr = lane & 15;
  const int lg = lane >> 4;
  const int bid = blockIdx.x;
  const int b  = bid & 7;                   // batch -> XCD affinity
  const int pp = bid >> 3;                  // pair index 0..15
  const int kvperm_base = (lr >> 2) * 8 + (lr & 3);

  const unsigned short* kbase = kb + (size_t)b * 2048 * 128;
  const unsigned short* vbase = vt + (size_t)b * 128 * 2048;

  #pragma unroll 1
  for (int tile = 0; tile < 2; ++tile) {
    const int T0 = (tile == 0) ? (31 - pp) * 64 : pp * 64;
    const int nb = (T0 >> 6) + 1;           // kv-blocks incl. diagonal
    const int myrow = T0 + wv * 16 + lr;

    // Q fragment: lane holds q-row myrow
    short8 qf[4];
    const unsigned short* qp = q + ((size_t)(b * 2048) + myrow) * 128 + lg * 8;
    #pragma unroll
    for (int ks = 0; ks < 4; ++ks)
      qf[ks] = *reinterpret_cast<const short8*>(qp + ks * 32);

    f32x4 o[8];
    #pragma unroll
    for (int n = 0; n < 8; ++n) o[n] = (f32x4){0.f, 0.f, 0.f, 0.f};
    float mrow = -1e30f;
    float lrow = 0.f;

    // ---- stage helper (inlined twice): K 1024 chunks, V 1024 chunks of 16B
    #define STAGE(KVB, BUF)                                                         \
      do {                                                                          \
        _Pragma("unroll")                                                           \
        for (int i = 0; i < 4; ++i) {                                               \
          int c = i * 256 + tid;                                                    \
          const unsigned short* g = kbase + (size_t)((KVB) + (c >> 4)) * 128 + (c & 15) * 8; \
          __builtin_amdgcn_global_load_lds((gas_u32p)g,                             \
              (las_u32p)&kl[BUF][(i * 256 + wv * 64) * 8], 16, 0, 0);               \
        }                                                                           \
        _Pragma("unroll")                                                           \
        for (int i = 0; i < 4; ++i) {                                               \
          int c = i * 256 + tid;                                                    \
          const unsigned short* g = vbase + (size_t)(c >> 3) * 2048 + (KVB) + (c & 7) * 8; \
          __builtin_amdgcn_global_load_lds((gas_u32p)g,                             \
              (las_u32p)&vl[BUF][(i * 256 + wv * 64) * 8], 16, 0, 0);               \
        }                                                                           \
      } while (0)

    STAGE(0, 0);
    __syncthreads();                         // includes vmcnt(0) drain

    #pragma unroll 1
    for (int ib = 0; ib < nb; ++ib) {
      const int cur = ib & 1;
      if (ib + 1 < nb) STAGE((ib + 1) * 64, cur ^ 1);   // async, drains at barrier
      if (ib == nb - 1)
        attn_body<true >(ib * 64, myrow, lr, lg, kvperm_base, kl[cur], vl[cur], qf, o, mrow, lrow);
      else
        attn_body<false>(ib * 64, myrow, lr, lg, kvperm_base, kl[cur], vl[cur], qf, o, mrow, lrow);
      __syncthreads();
    }
    #undef STAGE

    // epilogue: all in-lane (o^T col = q-row); contiguous float4 stores
    float rcp = 1.0f / lrow;
    float* op = out + ((size_t)(b * 2048) + myrow) * 128;
    #pragma unroll
    for (int n = 0; n < 8; ++n) {
      float4 st;
      st.x = o[n][0] * rcp; st.y = o[n][1] * rcp;
      st.z = o[n][2] * rcp; st.w = o[n][3] * rcp;
      *reinterpret_cast<float4*>(op + n * 16 + lg * 4) = st;
    }
  }
}

extern "C" void kernel_launch(void* const* d_in, const int* in_sizes, int n_in,
                              void* d_out, int out_size, void* d_ws, size_t ws_size,
                              hipStream_t stream) {
  const float* x  = (const float*)d_in[0];
  const float* Wk = (const float*)d_in[1];
  const float* Wq = (const float*)d_in[2];
  const float* Wv = (const float*)d_in[3];
  float* out = (float*)d_out;

  char* ws = (char*)d_ws;
  unsigned short* q  = (unsigned short*)(ws);                  // 4 MB
  unsigned short* kb = (unsigned short*)(ws + (4u  << 20));    // 4 MB (swizzled)
  unsigned short* vt = (unsigned short*)(ws + (8u  << 20));    // 4 MB (swizzled)
  unsigned short* Wt = (unsigned short*)(ws + (12u << 20));    // 768 KB

  wtrans_kernel<<<dim3(1536), dim3(256), 0, stream>>>(Wq, Wk, Wv, Wt);
  qkv_kernel<<<dim3(256), dim3(512), 0, stream>>>(x, Wt, q, kb, vt);
  attn_kernel<<<dim3(128), dim3(256), 0, stream>>>(q, kb, vt, out);
}